// Round 5
// baseline (48.334 us; speedup 1.0000x reference)
//
#include <hip/hip_runtime.h>

#define D_MAX   50
#define T_DIM   51
#define B_DIM   16
#define P_DIM   2048
#define Q_DIM   2048
#define TSTRIDE 80            // bytes per t-row: 64 used (16 b * u32 pair) + 16 skew
#define PBYTES  4096          // bytes per p-row: 51*80 = 4080, padded to 4096
#define PCH     8             // p's per LDS chunk (32 KB)
#define PSPAN   32            // p's per block (4 chunks)
#define NPBLK   (P_DIM / PSPAN)        // 64
#define QB      256
#define CHUNK_BYTES (PCH * PBYTES)     // 32768

// ws layout:
//   bufSw  : char [P][PBYTES] = 8 MiB.  u32 at p*4096 + t*80 + b*4 =
//            (bf16(buf[b][t][p]) , bf16(buf[b][t+1][p])<<16), t=0..50
//   partial: float [NPBLK][B][Q] = 8 MiB

typedef const __attribute__((address_space(1))) void* gas_ptr;
typedef __attribute__((address_space(3))) void* las_ptr;
__device__ __forceinline__ void async_copy16(const char* g, char* l) {
    __builtin_amdgcn_global_load_lds((gas_ptr)g, (las_ptr)l, 16, 0, 0);
}

__device__ __forceinline__ unsigned rne_bf16(float v) {
    unsigned x = __float_as_uint(v);
    x += 0x7fffu + ((x >> 16) & 1u);
    return x >> 16;
}

// Kernel 1: buf [B][T][P] -> packed bf16-pair image. Grid (128 p-tiles, 2 b-halves).
#define PT_TR 16
__global__ __launch_bounds__(256) void dsl_transpose_kernel(
    const float* __restrict__ buf, char* __restrict__ bufSw) {
    __shared__ float st[8][T_DIM + 1][PT_TR + 1];   // 28.3 KB
    const int p0 = blockIdx.x * PT_TR;
    const int b0 = blockIdx.y * 8;
    const int tid = threadIdx.x;

    // load: 16 p-lanes x 16 t-rows, per b-local
    const int pp = tid & 15, r0 = tid >> 4;
#pragma unroll
    for (int bl = 0; bl < 8; ++bl)
        for (int t = r0; t < T_DIM + 1; t += 16)
            st[bl][t][pp] = (t < T_DIM)
                ? buf[((size_t)((b0 + bl) * T_DIM + t)) * P_DIM + p0 + pp] : 0.f;
    __syncthreads();

    // store: 8 b-lanes (32B contiguous per (p,t)), 32 (p,t) slots per pass
    const int bl = tid & 7, k = tid >> 3;
    for (int j = k; j < PT_TR * T_DIM; j += 32) {
        const int p = j & 15, t = j >> 4;           // t = 0..50
        const unsigned u = rne_bf16(st[bl][t][p])
                         | (rne_bf16(st[bl][t + 1][p]) << 16);
        *(unsigned*)(bufSw + (size_t)(p0 + p) * PBYTES + t * TSTRIDE
                     + (b0 + bl) * 4) = u;
    }
}

// Kernel 2: block = 256 q-lanes x 32 p (4 chunks of 8, double-buffered LDS).
// Per (p,thread): sigmoid once, 4 ds_read_b128 (one 64B skewed row holds both
// taps for all 16 b), 16 unpack+dual-FMA.
__global__ __launch_bounds__(256) void dsl_main_kernel(
    const float* __restrict__ W, const float* __restrict__ DR,
    const char* __restrict__ bufSw, float* __restrict__ partial) {
    __shared__ char lds[2 * CHUNK_BYTES];   // 64 KB -> 2 blocks/CU
    const int tid = threadIdx.x;
    const int q   = blockIdx.x * QB + tid;
    const int p0  = blockIdx.y * PSPAN;
    const int wid = tid >> 6, lane = tid & 63;

    // fill chunk 0
    {
        const char* src = bufSw + (size_t)p0 * PBYTES + wid * 1024 + lane * 16;
#pragma unroll
        for (int i = 0; i < 8; ++i)
            async_copy16(src + i * 4096, lds + i * 4096 + wid * 1024);
    }
    __syncthreads();

    float acc[B_DIM];
#pragma unroll
    for (int b = 0; b < B_DIM; ++b) acc[b] = 0.f;

#pragma unroll 1
    for (int c = 0; c < PSPAN / PCH; ++c) {
        if (c + 1 < PSPAN / PCH) {      // prefetch next chunk into other buffer
            const char* src = bufSw + (size_t)(p0 + (c + 1) * PCH) * PBYTES
                            + wid * 1024 + lane * 16;
            char* dst = lds + ((c + 1) & 1) * CHUNK_BYTES + wid * 1024;
#pragma unroll
            for (int i = 0; i < 8; ++i)
                async_copy16(src + i * 4096, dst + i * 4096);
        }
        const char* cbase = lds + (c & 1) * CHUNK_BYTES;
        const float* Wp  = W  + (size_t)(p0 + c * PCH) * Q_DIM + q;
        const float* DRp = DR + (size_t)(p0 + c * PCH) * Q_DIM + q;

#pragma unroll 2
        for (int pl = 0; pl < PCH; ++pl) {
            const float w = Wp[pl * Q_DIM];
            const float x = DRp[pl * Q_DIM];
            const float d = 50.f / (1.f + __expf(-x));      // D_MAX * sigmoid
            const int df = min((int)d, D_MAX);
            const float a   = d - (float)df;
            const float wa  = w * a;
            const float wna = w - wa;

            const char* rb = cbase + pl * PBYTES + df * TSTRIDE;
            const uint4 u0 = *(const uint4*)(rb);
            const uint4 u1 = *(const uint4*)(rb + 16);
            const uint4 u2 = *(const uint4*)(rb + 32);
            const uint4 u3 = *(const uint4*)(rb + 48);

#define ACC(i, u) {                                                        \
            const float fl = __uint_as_float((u) << 16);                   \
            const float cl = __uint_as_float((u) & 0xffff0000u);           \
            acc[i] = fmaf(wna, fl, fmaf(wa, cl, acc[i])); }
            ACC(0,  u0.x) ACC(1,  u0.y) ACC(2,  u0.z) ACC(3,  u0.w)
            ACC(4,  u1.x) ACC(5,  u1.y) ACC(6,  u1.z) ACC(7,  u1.w)
            ACC(8,  u2.x) ACC(9,  u2.y) ACC(10, u2.z) ACC(11, u2.w)
            ACC(12, u3.x) ACC(13, u3.y) ACC(14, u3.z) ACC(15, u3.w)
#undef ACC
        }
        __syncthreads();    // drains prefetch DMA + retires reads of cbase
    }

    float* dst = partial + (size_t)blockIdx.y * (B_DIM * Q_DIM) + q;
#pragma unroll
    for (int b = 0; b < B_DIM; ++b)
        dst[(size_t)b * Q_DIM] = acc[b];    // coalesced along q
}

// Kernel 3: sum NPBLK partials; 64 outputs x 4 c-waves, LDS combine.
__global__ __launch_bounds__(256) void dsl_reduce_kernel(
    const float* __restrict__ partial, float* __restrict__ out) {
    __shared__ float lds[4][64];
    const int j = threadIdx.x & 63, w = threadIdx.x >> 6;
    const int idx = blockIdx.x * 64 + j;            // idx = b*Q + q
    float s = 0.f;
    for (int c = w; c < NPBLK; c += 4)
        s += partial[(size_t)c * (B_DIM * Q_DIM) + idx];
    lds[w][j] = s;
    __syncthreads();
    if (w == 0)
        out[idx] = lds[0][j] + lds[1][j] + lds[2][j] + lds[3][j];
}

extern "C" void kernel_launch(void* const* d_in, const int* in_sizes, int n_in,
                              void* d_out, int out_size, void* d_ws, size_t ws_size,
                              hipStream_t stream) {
    const float* buf = (const float*)d_in[0];   // [B, T, P]
    const float* W   = (const float*)d_in[1];   // [P, Q]
    const float* DR  = (const float*)d_in[2];   // [P, Q]
    float* out = (float*)d_out;                 // [B, Q]

    char* ws = (char*)d_ws;
    char*  bufSw   = ws;
    float* partial = (float*)(ws + (size_t)P_DIM * PBYTES);

    hipLaunchKernelGGL(dsl_transpose_kernel, dim3(P_DIM / PT_TR, 2), dim3(256), 0, stream,
                       buf, bufSw);
    hipLaunchKernelGGL(dsl_main_kernel, dim3(Q_DIM / QB, NPBLK), dim3(256), 0, stream,
                       W, DR, bufSw, partial);
    hipLaunchKernelGGL(dsl_reduce_kernel, dim3((B_DIM * Q_DIM) / 64), dim3(256), 0, stream,
                       partial, out);
}

// Round 6
// 38.501 us; speedup vs baseline: 1.2554x; 1.2554x over previous
//
#include <hip/hip_runtime.h>

#define D_MAX   50
#define T_DIM   51
#define B_DIM   16
#define P_DIM   2048
#define Q_DIM   2048
#define TSTRIDE 80            // bytes per t-row: 64 used (16 b * u32 pair) + 16 skew
#define PBYTES  4096          // bytes per p-row: 51*80 = 4080, padded to 4096
#define PCH     16            // p's per LDS chunk (64 KB)
#define PSPAN   32            // p's per block (2 chunks)
#define NPBLK   (P_DIM / PSPAN)        // 64
#define QB      512
#define CHUNK_BYTES (PCH * PBYTES)     // 65536

// ws layout:
//   bufSw  : char [P][PBYTES] = 8 MiB.  u32 at p*4096 + t*80 + b*4 =
//            (bf16(buf[b][t][p]) | bf16(buf[b][t+1][p])<<16), t=0..50
//   partial: float [NPBLK][B][Q] = 8 MiB

typedef const __attribute__((address_space(1))) void* gas_ptr;
typedef __attribute__((address_space(3))) void* las_ptr;
__device__ __forceinline__ void async_copy16(const char* g, char* l) {
    __builtin_amdgcn_global_load_lds((gas_ptr)g, (las_ptr)l, 16, 0, 0);
}

__device__ __forceinline__ unsigned rne_bf16(float v) {
    unsigned x = __float_as_uint(v);
    x += 0x7fffu + ((x >> 16) & 1u);
    return x >> 16;
}
// d = taps.lo*cw.lo + taps.hi*cw.hi + acc   (bf16 pair dot, f32 accumulate)
__device__ __forceinline__ float dot2bf(unsigned taps, unsigned cw, float acc) {
    float d;
    asm("v_dot2_f32_bf16 %0, %1, %2, %3" : "=v"(d) : "v"(taps), "v"(cw), "v"(acc));
    return d;
}
__device__ __forceinline__ unsigned pack_bf16x2(float lo, float hi) {
    unsigned r;
    asm("v_cvt_pk_bf16_f32 %0, %1, %2" : "=v"(r) : "v"(lo), "v"(hi));
    return r;
}

// Kernel 1: buf [B][T][P] -> packed bf16-pair image (proven in R5, unchanged).
#define PT_TR 16
__global__ __launch_bounds__(256) void dsl_transpose_kernel(
    const float* __restrict__ buf, char* __restrict__ bufSw) {
    __shared__ float st[8][T_DIM + 1][PT_TR + 1];   // 28.3 KB
    const int p0 = blockIdx.x * PT_TR;
    const int b0 = blockIdx.y * 8;
    const int tid = threadIdx.x;

    const int pp = tid & 15, r0 = tid >> 4;
#pragma unroll
    for (int bl = 0; bl < 8; ++bl)
        for (int t = r0; t < T_DIM + 1; t += 16)
            st[bl][t][pp] = (t < T_DIM)
                ? buf[((size_t)((b0 + bl) * T_DIM + t)) * P_DIM + p0 + pp] : 0.f;
    __syncthreads();

    const int bl = tid & 7, k = tid >> 3;
    for (int j = k; j < PT_TR * T_DIM; j += 32) {
        const int p = j & 15, t = j >> 4;           // t = 0..50
        const unsigned u = rne_bf16(st[bl][t][p])
                         | (rne_bf16(st[bl][t + 1][p]) << 16);
        *(unsigned*)(bufSw + (size_t)(p0 + p) * PBYTES + t * TSTRIDE
                     + (b0 + bl) * 4) = u;
    }
}

// Kernel 2: R4's proven schedule (512 thr, 2 chunks of 16 p, 2 barriers) +
// bf16 taps + v_dot2 + chunk-level W/DR register preload + XCD grouping.
#define COMPUTE_CHUNK(base, wpf, xpf)                                       \
    _Pragma("unroll")                                                       \
    for (int pl = 0; pl < PCH; ++pl) {                                      \
        const float w = (wpf)[pl], x = (xpf)[pl];                           \
        const float d = 50.f / (1.f + __expf(-x));                          \
        const int df = min((int)d, D_MAX);                                  \
        const float a  = d - (float)df;                                     \
        const float wa = w * a;                                             \
        const unsigned cw = pack_bf16x2(w - wa, wa);                        \
        const char* rb = (base) + pl * PBYTES + df * TSTRIDE;               \
        const uint4 u0 = *(const uint4*)(rb);                               \
        const uint4 u1 = *(const uint4*)(rb + 16);                          \
        const uint4 u2 = *(const uint4*)(rb + 32);                          \
        const uint4 u3 = *(const uint4*)(rb + 48);                          \
        acc[0]  = dot2bf(u0.x, cw, acc[0]);                                 \
        acc[1]  = dot2bf(u0.y, cw, acc[1]);                                 \
        acc[2]  = dot2bf(u0.z, cw, acc[2]);                                 \
        acc[3]  = dot2bf(u0.w, cw, acc[3]);                                 \
        acc[4]  = dot2bf(u1.x, cw, acc[4]);                                 \
        acc[5]  = dot2bf(u1.y, cw, acc[5]);                                 \
        acc[6]  = dot2bf(u1.z, cw, acc[6]);                                 \
        acc[7]  = dot2bf(u1.w, cw, acc[7]);                                 \
        acc[8]  = dot2bf(u2.x, cw, acc[8]);                                 \
        acc[9]  = dot2bf(u2.y, cw, acc[9]);                                 \
        acc[10] = dot2bf(u2.z, cw, acc[10]);                                \
        acc[11] = dot2bf(u2.w, cw, acc[11]);                                \
        acc[12] = dot2bf(u3.x, cw, acc[12]);                                \
        acc[13] = dot2bf(u3.y, cw, acc[13]);                                \
        acc[14] = dot2bf(u3.z, cw, acc[14]);                                \
        acc[15] = dot2bf(u3.w, cw, acc[15]);                                \
    }

__global__ __launch_bounds__(512) void dsl_main_kernel(
    const float* __restrict__ W, const float* __restrict__ DR,
    const char* __restrict__ bufSw, float* __restrict__ partial) {
    __shared__ char lds[2 * CHUNK_BYTES];   // 128 KB
    const int tid = threadIdx.x;
    // XCD grouping: the 4 q-col blocks of one p-range land on one XCD's L2.
    const int i  = blockIdx.x + 4 * blockIdx.y;            // dispatch-linear
    const int xq = i >> 6;
    const int yp = ((i & 7) << 3) | ((i >> 3) & 7);        // bijective on [0,64)
    const int q  = xq * QB + tid;
    const int p0 = yp * PSPAN;
    const int wid = tid >> 6, lane = tid & 63;

    // fill chunk 0 (64 KB): 8 x (512 thr * 16 B), linear LDS dest
    {
        const char* src = bufSw + (size_t)p0 * PBYTES + wid * 1024 + lane * 16;
        char* dst = lds + wid * 1024;
#pragma unroll
        for (int k = 0; k < 8; ++k)
            async_copy16(src + k * 8192, dst + k * 8192);
    }
    // preload chunk-0 W/DR into registers (32 loads in flight together)
    const float* Wq = W + q;
    const float* Dq = DR + q;
    float wpf0[PCH], xpf0[PCH];
#pragma unroll
    for (int j = 0; j < PCH; ++j) {
        wpf0[j] = Wq[(size_t)(p0 + j) * Q_DIM];
        xpf0[j] = Dq[(size_t)(p0 + j) * Q_DIM];
    }
    __syncthreads();

    // issue chunk-1 DMA + W/DR preload; both hide under chunk-0 compute
    {
        const char* src = bufSw + (size_t)(p0 + PCH) * PBYTES + wid * 1024 + lane * 16;
        char* dst = lds + CHUNK_BYTES + wid * 1024;
#pragma unroll
        for (int k = 0; k < 8; ++k)
            async_copy16(src + k * 8192, dst + k * 8192);
    }
    float wpf1[PCH], xpf1[PCH];
#pragma unroll
    for (int j = 0; j < PCH; ++j) {
        wpf1[j] = Wq[(size_t)(p0 + PCH + j) * Q_DIM];
        xpf1[j] = Dq[(size_t)(p0 + PCH + j) * Q_DIM];
    }

    float acc[B_DIM];
#pragma unroll
    for (int b = 0; b < B_DIM; ++b) acc[b] = 0.f;

    COMPUTE_CHUNK(lds, wpf0, xpf0)
    __syncthreads();                        // drains chunk-1 DMA
    COMPUTE_CHUNK(lds + CHUNK_BYTES, wpf1, xpf1)

    float* dst = partial + (size_t)yp * (B_DIM * Q_DIM) + q;
#pragma unroll
    for (int b = 0; b < B_DIM; ++b)
        dst[(size_t)b * Q_DIM] = acc[b];    // coalesced along q
}

// Kernel 3: sum NPBLK partials; 64 outputs x 4 c-waves, LDS combine.
__global__ __launch_bounds__(256) void dsl_reduce_kernel(
    const float* __restrict__ partial, float* __restrict__ out) {
    __shared__ float lds[4][64];
    const int j = threadIdx.x & 63, w = threadIdx.x >> 6;
    const int idx = blockIdx.x * 64 + j;            // idx = b*Q + q
    float s = 0.f;
    for (int c = w; c < NPBLK; c += 4)
        s += partial[(size_t)c * (B_DIM * Q_DIM) + idx];
    lds[w][j] = s;
    __syncthreads();
    if (w == 0)
        out[idx] = lds[0][j] + lds[1][j] + lds[2][j] + lds[3][j];
}

extern "C" void kernel_launch(void* const* d_in, const int* in_sizes, int n_in,
                              void* d_out, int out_size, void* d_ws, size_t ws_size,
                              hipStream_t stream) {
    const float* buf = (const float*)d_in[0];   // [B, T, P]
    const float* W   = (const float*)d_in[1];   // [P, Q]
    const float* DR  = (const float*)d_in[2];   // [P, Q]
    float* out = (float*)d_out;                 // [B, Q]

    char* ws = (char*)d_ws;
    char*  bufSw   = ws;
    float* partial = (float*)(ws + (size_t)P_DIM * PBYTES);

    hipLaunchKernelGGL(dsl_transpose_kernel, dim3(P_DIM / PT_TR, 2), dim3(256), 0, stream,
                       buf, bufSw);
    hipLaunchKernelGGL(dsl_main_kernel, dim3(Q_DIM / QB, NPBLK), dim3(512), 0, stream,
                       W, DR, bufSw, partial);
    hipLaunchKernelGGL(dsl_reduce_kernel, dim3((B_DIM * Q_DIM) / 64), dim3(256), 0, stream,
                       partial, out);
}

// Round 7
// 23.988 us; speedup vs baseline: 2.0149x; 1.6050x over previous
//
#include <hip/hip_runtime.h>

#define D_MAX   50
#define T_DIM   51
#define B_DIM   16
#define P_DIM   2048
#define Q_DIM   2048
#define TSTRIDE 80            // bytes per t-row: 64 used (16 b * u32 pair) + 16 skew
#define PBY     4112          // LDS bytes per p-row: 51*80=4080 pad to 16-mult, 4-bank p-rotate
#define PSPAN   32            // p's per block
#define NPBLK   (P_DIM / PSPAN)        // 64
#define QB      512

// ws layout: partial float [NPBLK][B][Q] = 64*16*2048*4 = 8 MiB

// d = taps.lo*cw.lo + taps.hi*cw.hi + acc   (bf16 pair dot, f32 accumulate)
__device__ __forceinline__ float dot2bf(unsigned taps, unsigned cw, float acc) {
    float d;
    asm("v_dot2_f32_bf16 %0, %1, %2, %3" : "=v"(d) : "v"(taps), "v"(cw), "v"(acc));
    return d;
}
__device__ __forceinline__ unsigned pack_bf16x2(float lo, float hi) {
    unsigned r;
    asm("v_cvt_pk_bf16_f32 %0, %1, %2" : "=v"(r) : "v"(lo), "v"(hi));
    return r;
}

// Fused kernel: block = 512 q-lanes, 32 p. Phase 1: pack bf16 tap-pair image
// for this block's p-slice straight from buf into LDS (thread=(b,p) owns a
// t-run in registers). Phase 2: per p, sigmoid once, 4 ds_read_b128 (one 64B
// skewed row holds both taps for all 16 b), 16 v_dot2.
__global__ __launch_bounds__(512, 2) void dsl_fused_kernel(
    const float* __restrict__ buf, const float* __restrict__ W,
    const float* __restrict__ DR, float* __restrict__ partial) {
    __shared__ char lds[PSPAN * PBY];   // 131,584 B
    const int tid = threadIdx.x;
    // XCD grouping: the 4 q-col blocks of one p-slice are 64 apart in dispatch
    // order -> same XCD (64 % 8 == 0); scramble spreads p-slices across XCDs.
    const int i  = blockIdx.x;
    const int xq = i >> 6;                            // 0..3 q-column
    const int yp = ((i & 7) << 3) | ((i >> 3) & 7);   // bijective on [0,64)
    const int q  = xq * QB + tid;
    const int p0 = yp * PSPAN;

    // ---- phase 1: pack. thread = (b = tid>>5, p = tid&31)
    const int bb = tid >> 5, pl = tid & 31;
    const float* src = buf + (size_t)bb * (T_DIM * P_DIM) + p0 + pl;
    float v[T_DIM + 1];
#pragma unroll
    for (int t = 0; t < T_DIM; ++t)
        v[t] = src[(size_t)t * P_DIM];    // lanes: 2 x 128B segments per t
    v[T_DIM] = 0.f;                       // ceil-tap for t=50 (alpha=0 there only if d==50)
    {
        char* wb = lds + pl * PBY + bb * 4;
#pragma unroll
        for (int t = 0; t < T_DIM; ++t)   // rows 0..50; row t holds (v[t],v[t+1])
            *(unsigned*)(wb + t * TSTRIDE) = pack_bf16x2(v[t], v[t + 1]);
    }

    // ---- W/DR register preload (issues while ds_writes drain)
    const float* Wq = W + q;
    const float* Dq = DR + q;
    float wpf[PSPAN], xpf[PSPAN];
#pragma unroll
    for (int j = 0; j < PSPAN; ++j) {
        wpf[j] = Wq[(size_t)(p0 + j) * Q_DIM];
        xpf[j] = Dq[(size_t)(p0 + j) * Q_DIM];
    }
    __syncthreads();

    // ---- phase 2: compute
    float acc[B_DIM];
#pragma unroll
    for (int b = 0; b < B_DIM; ++b) acc[b] = 0.f;

#pragma unroll
    for (int p = 0; p < PSPAN; ++p) {
        const float w = wpf[p], x = xpf[p];
        const float d = 50.f / (1.f + __expf(-x));    // D_MAX * sigmoid
        const int df = min((int)d, D_MAX);
        const float a  = d - (float)df;
        const float wa = w * a;
        const unsigned cw = pack_bf16x2(w - wa, wa);
        const char* rb = lds + p * PBY + df * TSTRIDE;
        const uint4 u0 = *(const uint4*)(rb);
        const uint4 u1 = *(const uint4*)(rb + 16);
        const uint4 u2 = *(const uint4*)(rb + 32);
        const uint4 u3 = *(const uint4*)(rb + 48);
        acc[0]  = dot2bf(u0.x, cw, acc[0]);
        acc[1]  = dot2bf(u0.y, cw, acc[1]);
        acc[2]  = dot2bf(u0.z, cw, acc[2]);
        acc[3]  = dot2bf(u0.w, cw, acc[3]);
        acc[4]  = dot2bf(u1.x, cw, acc[4]);
        acc[5]  = dot2bf(u1.y, cw, acc[5]);
        acc[6]  = dot2bf(u1.z, cw, acc[6]);
        acc[7]  = dot2bf(u1.w, cw, acc[7]);
        acc[8]  = dot2bf(u2.x, cw, acc[8]);
        acc[9]  = dot2bf(u2.y, cw, acc[9]);
        acc[10] = dot2bf(u2.z, cw, acc[10]);
        acc[11] = dot2bf(u2.w, cw, acc[11]);
        acc[12] = dot2bf(u3.x, cw, acc[12]);
        acc[13] = dot2bf(u3.y, cw, acc[13]);
        acc[14] = dot2bf(u3.z, cw, acc[14]);
        acc[15] = dot2bf(u3.w, cw, acc[15]);
    }

    float* dst = partial + (size_t)yp * (B_DIM * Q_DIM) + q;
#pragma unroll
    for (int b = 0; b < B_DIM; ++b)
        dst[(size_t)b * Q_DIM] = acc[b];    // coalesced along q
}

// Reduce: sum NPBLK partials; block = 64 outputs x 4 c-waves, LDS combine.
__global__ __launch_bounds__(256) void dsl_reduce_kernel(
    const float* __restrict__ partial, float* __restrict__ out) {
    __shared__ float lds[4][64];
    const int j = threadIdx.x & 63, w = threadIdx.x >> 6;
    const int idx = blockIdx.x * 64 + j;            // idx = b*Q + q
    float s = 0.f;
    for (int c = w; c < NPBLK; c += 4)
        s += partial[(size_t)c * (B_DIM * Q_DIM) + idx];
    lds[w][j] = s;
    __syncthreads();
    if (w == 0)
        out[idx] = lds[0][j] + lds[1][j] + lds[2][j] + lds[3][j];
}

extern "C" void kernel_launch(void* const* d_in, const int* in_sizes, int n_in,
                              void* d_out, int out_size, void* d_ws, size_t ws_size,
                              hipStream_t stream) {
    const float* buf = (const float*)d_in[0];   // [B, T, P]
    const float* W   = (const float*)d_in[1];   // [P, Q]
    const float* DR  = (const float*)d_in[2];   // [P, Q]
    float* out = (float*)d_out;                 // [B, Q]

    float* partial = (float*)d_ws;              // [NPBLK][B][Q], 8 MiB

    hipLaunchKernelGGL(dsl_fused_kernel, dim3(256), dim3(512), 0, stream,
                       buf, W, DR, partial);
    hipLaunchKernelGGL(dsl_reduce_kernel, dim3((B_DIM * Q_DIM) / 64), dim3(256), 0, stream,
                       partial, out);
}